// Round 9
// baseline (1726.727 us; speedup 1.0000x reference)
//
#include <hip/hip_runtime.h>

// SNN forward, exact fixed-point int8 MFMA, fused GEMM+leaky-IF per layer.
// Each block owns a 32x32 output tile and loops timesteps with membrane state
// in registers; per t: reg-pipelined LDS-staged K-loop -> IF epilogue.
// Numerics identical to rounds 4-8 (all passed): spikes exact in i8; W = 5
// balanced base-256 digits of round(w*2^40); x digitized to round(x*2^36)
// (pairs p+q>=4 kept); i32 MFMA accumulation exact; fp64 reconstruction.

typedef int int4v __attribute__((ext_vector_type(4)));

#define XSCALE 68719476736.0      // 2^36
#define WSCALE 1099511627776.0    // 2^40
#define TC0 10                    // layer-0 timestep chunk (xsb sizing)

// ---- W digit split: fp32 [Nreal][K] -> 5 planes [Npad][Kpad], zero-padded ----
__global__ void wsplit_i8(const float* __restrict__ W, signed char* __restrict__ out,
                          int Nreal, int Npad, int K, int Kpad)
{
    int idx = blockIdx.x * blockDim.x + threadIdx.x;
    int total = Npad * Kpad;
    if (idx >= total) return;
    int n = idx / Kpad, k = idx - n * Kpad;
    long long v = 0;
    if (n < Nreal && k < K) v = __double2ll_rn((double)W[(size_t)n * K + k] * WSCALE);
    size_t plane = (size_t)total;
#pragma unroll
    for (int p = 0; p < 4; ++p) {
        int d = (int)(v & 255); if (d > 127) d -= 256;
        out[p * plane + idx] = (signed char)d;
        v = (v - d) >> 8;
    }
    out[4 * plane + idx] = (signed char)v;
}

// ---- x chunk digitize: [TC0*512][784] fp32 -> 5 planes [5120][832] ----
__global__ void xsplit_chunk(const float* __restrict__ x, signed char* __restrict__ out)
{
    int idx = blockIdx.x * blockDim.x + threadIdx.x;
    if (idx >= 5120 * 832) return;
    int row = idx / 832, k = idx - row * 832;
    long long v = 0;
    if (k < 784) v = __double2ll_rn((double)x[(size_t)row * 784 + k] * XSCALE);
    const size_t plane = (size_t)5120 * 832;
    signed char* o = out + idx;
#pragma unroll
    for (int p = 0; p < 4; ++p) {
        int d = (int)(v & 255); if (d > 127) d -= 256;
        o[p * plane] = (signed char)d;
        v = (v - d) >> 8;
    }
    o[4 * plane] = (signed char)v;
}

// ---- fused kernel ----
// NA: A digit planes (5 = layer0 TRI, 1 = spike input). KP: padded K.
// MODE 0: IF epilogue (spk/mem/spk_i8 outputs, state in regs over TCNT steps).
// MODE 1: raw fp64 cur output (layer 3 batched GEMM; TCNT=1, grid.x = M/32).
// Block: 256 thr = 4 waves; tile 32(M) x 32(N); wave tile 16x16.
template<int NA, int KP, int MODE>
__global__ __launch_bounds__(256)
void snn_fused(const signed char* __restrict__ Ab, size_t planeA,
               const signed char* __restrict__ Wp, size_t planeW,
               const float* __restrict__ bias,
               double* __restrict__ mw, int first,
               float* __restrict__ spk, float* __restrict__ mem,
               signed char* __restrict__ spk_i8,
               double* __restrict__ curout,
               int N, int t0, int TCNT)
{
    __shared__ __align__(16) signed char Wld[5 * 32 * 80];
    __shared__ __align__(16) signed char Ald[NA * 32 * 80];
    constexpr int NIT = KP / 64;

    const int tid = threadIdx.x;
    const int l   = tid & 63;
    const int w   = tid >> 6;          // 0..3
    const int wm  = (w & 1) * 16;
    const int wn  = (w >> 1) * 16;
    const int fr  = l & 15;
    const int g   = l >> 4;            // 16B chunk select

    int m_tile, n_tile;
    if constexpr (MODE == 1) { m_tile = blockIdx.x; n_tile = 0; }
    else {
        int wgid = (blockIdx.x & 7) * 64 + (blockIdx.x >> 3);  // bijective (512=8*64)
        n_tile = wgid >> 4; m_tile = wgid & 15;                // n-major per XCD
    }
    const int bm = m_tile * 32;
    const int bn = n_tile * 32;

    const int srow = tid >> 3;         // 0..31
    const int c8   = (tid & 7) * 8;    // 0..56

    const signed char* wg = Wp + (size_t)(bn + srow) * KP + c8;   // rows zero-padded
    const signed char* ag = Ab + (size_t)(bm + srow) * KP + c8;   // t=0 rows

    // membrane state (4 outputs/lane)
    double ms[4];
    const int col = bn + wn + fr;
    if constexpr (MODE == 0) {
        if (first) {
#pragma unroll
            for (int r = 0; r < 4; ++r) ms[r] = 0.0;
        } else {
#pragma unroll
            for (int r = 0; r < 4; ++r)
                ms[r] = mw[(size_t)(bm + wm + 4 * g + r) * 1024 + col];
        }
    }

    // prologue: k-block 0 into regs
    unsigned long long Wr[5], Ar[NA];
#pragma unroll
    for (int p = 0; p < 5; ++p) Wr[p] = *(const unsigned long long*)(wg + p * planeW);
#pragma unroll
    for (int p = 0; p < NA; ++p) Ar[p] = *(const unsigned long long*)(ag + p * planeA);

    int4v acc[5];
#pragma unroll
    for (int s = 0; s < 5; ++s) acc[s] = (int4v){0, 0, 0, 0};

    for (int tt = 0; tt < TCNT; ++tt) {
        for (int it = 0; it < NIT; ++it) {
            __syncthreads();
#pragma unroll
            for (int p = 0; p < 5; ++p)
                *(unsigned long long*)&Wld[(p * 32 + srow) * 80 + c8] = Wr[p];
#pragma unroll
            for (int p = 0; p < NA; ++p)
                *(unsigned long long*)&Ald[(p * 32 + srow) * 80 + c8] = Ar[p];
            __syncthreads();

            // advance + prefetch next k-block (wraps to next timestep)
            bool valid;
            if (it + 1 < NIT)      { wg += 64; ag += 64; valid = true; }
            else if (tt + 1 < TCNT){ wg -= (NIT - 1) * 64;
                                     ag += (size_t)512 * KP - (NIT - 1) * 64; valid = true; }
            else valid = false;
            if (valid) {
#pragma unroll
                for (int p = 0; p < 5; ++p)
                    Wr[p] = *(const unsigned long long*)(wg + p * planeW);
#pragma unroll
                for (int p = 0; p < NA; ++p)
                    Ar[p] = *(const unsigned long long*)(ag + p * planeA);
            }

            int4v af[NA];
#pragma unroll
            for (int p = 0; p < NA; ++p)
                af[p] = *(const int4v*)&Ald[(p * 32 + wm + fr) * 80 + 16 * g];
#pragma unroll
            for (int q = 0; q < 5; ++q) {
                int4v bq = *(const int4v*)&Wld[(q * 32 + wn + fr) * 80 + 16 * g];
                if constexpr (NA == 5) {
#pragma unroll
                    for (int p = 0; p < 5; ++p)
                        if (p + q >= 4)
                            acc[p + q - 4] = __builtin_amdgcn_mfma_i32_16x16x64_i8(
                                af[p], bq, acc[p + q - 4], 0, 0, 0);
                } else {
                    acc[q] = __builtin_amdgcn_mfma_i32_16x16x64_i8(
                        af[0], bq, acc[q], 0, 0, 0);
                }
            }
        }

        // ---- per-timestep epilogue; C/D: col=l&15, row=4*(l>>4)+r ----
        const int t = t0 + tt;
        if constexpr (MODE == 1) {
            if (col < 16) {
#pragma unroll
                for (int r = 0; r < 4; ++r) {
                    int row = bm + wm + 4 * g + r;
                    double v = (double)acc[4][r];
                    v = v * 256.0 + (double)acc[3][r];
                    v = v * 256.0 + (double)acc[2][r];
                    v = v * 256.0 + (double)acc[1][r];
                    v = v * 256.0 + (double)acc[0][r];
                    curout[(size_t)row * 16 + col] = v * 0x1p-40;
                }
            }
        } else {
            if (col < N) {
                double bs = (double)bias[col];
#pragma unroll
                for (int r = 0; r < 4; ++r) {
                    int row = bm + wm + 4 * g + r;
                    double v = (double)acc[4][r];
                    v = v * 256.0 + (double)acc[3][r];
                    v = v * 256.0 + (double)acc[2][r];
                    v = v * 256.0 + (double)acc[1][r];
                    v = v * 256.0 + (double)acc[0][r];
                    double cur = v * (NA == 5 ? 0x1p-44 : 0x1p-40) + bs;
                    double mp  = ms[r];
                    double rst = (mp > 1.0) ? 1.0 : 0.0;
                    double mn  = 0.9 * mp + cur - rst;
                    size_t o = ((size_t)t * 512 + row) * N + col;
                    spk[o] = (mn > 1.0) ? 1.0f : 0.0f;
                    mem[o] = (float)mn;
                    if (spk_i8)
                        spk_i8[((size_t)t * 512 + row) * 1024 + col] =
                            (signed char)((mn > 1.0) ? 1 : 0);
                    ms[r] = mn;
                }
            }
        }
#pragma unroll
        for (int s = 0; s < 5; ++s) acc[s] = (int4v){0, 0, 0, 0};
    }

    if constexpr (MODE == 0) {
        if (mw) {
#pragma unroll
            for (int r = 0; r < 4; ++r)
                mw[(size_t)(bm + wm + 4 * g + r) * 1024 + col] = ms[r];
        }
    }
}

// ---- layer-3 IF chain: 5120 neurons, all 50 t in registers ----
__global__ __launch_bounds__(256)
void if3_kernel(const double* __restrict__ cur3, const float* __restrict__ bias,
                float* __restrict__ spk3, float* __restrict__ mem3)
{
    int idx = blockIdx.x * blockDim.x + threadIdx.x;
    if (idx >= 5120) return;
    int brow = idx / 10, col = idx - brow * 10;
    double bs = (double)bias[col];
    double mp = 0.0;
    for (int t = 0; t < 50; ++t) {
        double c   = cur3[((size_t)t * 512 + brow) * 16 + col] + bs;
        double rst = (mp > 1.0) ? 1.0 : 0.0;
        double mn  = 0.9 * mp + c - rst;
        size_t o   = (size_t)t * 5120 + (size_t)brow * 10 + col;
        spk3[o] = (mn > 1.0) ? 1.0f : 0.0f;
        mem3[o] = (float)mn;
        mp = mn;
    }
}

extern "C" void kernel_launch(void* const* d_in, const int* in_sizes, int n_in,
                              void* d_out, int out_size, void* d_ws, size_t ws_size,
                              hipStream_t stream)
{
    const float* x  = (const float*)d_in[0];
    const float* W0 = (const float*)d_in[1];
    const float* b0 = (const float*)d_in[2];
    const float* W1 = (const float*)d_in[3];
    const float* b1 = (const float*)d_in[4];
    const float* W2 = (const float*)d_in[5];
    const float* b2 = (const float*)d_in[6];
    const float* W3 = (const float*)d_in[7];
    const float* b3 = (const float*)d_in[8];
    float* out = (float*)d_out;

    const int T = 50;
    const size_t LNH = (size_t)512 * 1000;
    const size_t LNO = (size_t)512 * 10;

    float* spk0 = out;
    float* spk1 = spk0 + (size_t)T * LNH;
    float* spk2 = spk1 + (size_t)T * LNH;
    float* spk3 = spk2 + (size_t)T * LNH;
    float* mem0 = spk3 + (size_t)T * LNO;
    float* mem1 = mem0 + (size_t)T * LNH;
    float* mem2 = mem1 + (size_t)T * LNH;
    float* mem3 = mem2 + (size_t)T * LNH;

    // ---- workspace layout: fp64 first, then i8 ----
    double* cur3 = (double*)d_ws;                         // 25600*16*8 = 3.28 MB
    double* mw0  = cur3 + (size_t)25600 * 16;             // 512*1024*8 = 4.19 MB
    signed char* W0d = (signed char*)(mw0 + (size_t)512 * 1024);  // 5*1024*832
    signed char* W1d = W0d + (size_t)5 * 1024 * 832;      // 5*1024*1024
    signed char* W2d = W1d + (size_t)5 * 1024 * 1024;
    signed char* W3d = W2d + (size_t)5 * 1024 * 1024;     // 5*64*1024
    signed char* xsb = W3d + (size_t)5 * 64 * 1024;       // 5*5120*832 = 21.3 MB
    signed char* sp0 = xsb + (size_t)5 * 5120 * 832;      // full-T: 50*512*1024 each
    signed char* sp1 = sp0 + (size_t)50 * 512 * 1024;
    signed char* sp2 = sp1 + (size_t)50 * 512 * 1024;

    // zero spike buffers once (K-tail cols 1000..1023 must stay 0)
    hipMemsetAsync(sp0, 0, (size_t)3 * 50 * 512 * 1024, stream);

    // W digit splits
    wsplit_i8<<<(1024 * 832  + 255) / 256, 256, 0, stream>>>(W0, W0d, 1000, 1024, 784,  832);
    wsplit_i8<<<(1024 * 1024 + 255) / 256, 256, 0, stream>>>(W1, W1d, 1000, 1024, 1000, 1024);
    wsplit_i8<<<(1024 * 1024 + 255) / 256, 256, 0, stream>>>(W2, W2d, 1000, 1024, 1000, 1024);
    wsplit_i8<<<(64 * 1024   + 255) / 256, 256, 0, stream>>>(W3, W3d, 10,   64,   1000, 1024);

    const size_t plA0 = (size_t)5120 * 832;
    const size_t plW0 = (size_t)1024 * 832;
    const size_t plWH = (size_t)1024 * 1024;
    const size_t plW3 = (size_t)64 * 1024;

    // layer 0: 5 chunks of TC0=10 (membrane carried in mw0 between chunks)
    for (int c = 0; c < T / TC0; ++c) {
        xsplit_chunk<<<(5120 * 832 + 255) / 256, 256, 0, stream>>>(
            x + (size_t)c * TC0 * 512 * 784, xsb);
        snn_fused<5, 832, 0><<<512, 256, 0, stream>>>(
            xsb, plA0, W0d, plW0, b0, mw0, c == 0,
            spk0, mem0, sp0, nullptr, 1000, c * TC0, TC0);
    }
    // layers 1,2: all 50 timesteps in one kernel (state in regs)
    snn_fused<1, 1024, 0><<<512, 256, 0, stream>>>(
        sp0, 0, W1d, plWH, b1, nullptr, 1,
        spk1, mem1, sp1, nullptr, 1000, 0, T);
    snn_fused<1, 1024, 0><<<512, 256, 0, stream>>>(
        sp1, 0, W2d, plWH, b2, nullptr, 1,
        spk2, mem2, sp2, nullptr, 1000, 0, T);
    // layer 3: batched GEMM over M=25600, then tiny IF chain
    snn_fused<1, 1024, 1><<<800, 256, 0, stream>>>(
        sp2, 0, W3d, plW3, nullptr, nullptr, 1,
        nullptr, nullptr, nullptr, cur3, 10, 0, 1);
    if3_kernel<<<20, 256, 0, stream>>>(cur3, b3, spk3, mem3);
}

// Round 10
// 1535.439 us; speedup vs baseline: 1.1246x; 1.1246x over previous
//
#include <hip/hip_runtime.h>

// SNN forward, exact fixed-point int8 MFMA, decoupled batched-GEMM structure
// (round-8 skeleton) with a rebuilt high-intensity GEMM inner loop.
//   cur(l,t) = spk(l-1,t) @ W_l  -> batched over TC=10 timesteps (M=5120).
//   leaky-IF recursion only in cheap elementwise kernels (state in regs/mw).
// Numerics identical to rounds 4-9 (all passed): spikes exact in i8; W = 5
// balanced base-256 digits of round(w*2^40); x digitized on the fly to
// round(x*2^36) (digit pairs p+q>=4); i32 MFMA accumulation exact; cur stored
// fp64 (<2^53 exact, pow2 scale); IF chain fp64.

typedef int int4v __attribute__((ext_vector_type(4)));

#define XSCALE 68719476736.0      // 2^36
#define WSCALE 1099511627776.0    // 2^40
#define TC 10

// ---- W digit split: fp32 [Nreal][K] -> 5 planes [Npad][Kpad], zero-padded ----
__global__ void wsplit_i8(const float* __restrict__ W, signed char* __restrict__ out,
                          int Nreal, int Npad, int K, int Kpad)
{
    int idx = blockIdx.x * blockDim.x + threadIdx.x;
    int total = Npad * Kpad;
    if (idx >= total) return;
    int n = idx / Kpad, k = idx - n * Kpad;
    long long v = 0;
    if (n < Nreal && k < K) v = __double2ll_rn((double)W[(size_t)n * K + k] * WSCALE);
    size_t plane = (size_t)total;
#pragma unroll
    for (int p = 0; p < 4; ++p) {
        int d = (int)(v & 255); if (d > 127) d -= 256;
        out[p * plane + idx] = (signed char)d;
        v = (v - d) >> 8;
    }
    out[4 * plane + idx] = (signed char)v;
}

// ---- GEMM: cur[M][CS-strided] (fp64) = A @ W^T, exact int8 digit MFMA ----
// NA=5: A = x fp32 digitized on the fly (L0, triangular pairs p+q>=4).
// NA=1: A = spike i8 plane. Block 512 thr = 8 waves; tile 64(M) x 64(N);
// waves 2M x 4N, wave tile 32x16 (2 m-frags share the 5 bq reads).
template<int NA, int KP, int CS>
__global__ __launch_bounds__(512, 4)
void gemm_i8(const float* __restrict__ xsrc,
             const signed char* __restrict__ Asp,
             const signed char* __restrict__ Wp, size_t planeW,
             double* __restrict__ curout)
{
    __shared__ __align__(16) signed char Wld[5 * 64 * 80];       // 25.6 KB
    __shared__ __align__(16) signed char Ald[NA * 64 * 80];
    constexpr int NIT = KP / 64;

    const int tid = threadIdx.x;
    const int l   = tid & 63;
    const int wv  = tid >> 6;            // 0..7
    const int wmo = (wv & 1) * 32;       // wave m offset: 0/32
    const int wno = (wv >> 1) * 16;      // wave n offset: 0..48
    const int fr  = l & 15;
    const int g   = l >> 4;              // 16B chunk select

    const int bm = blockIdx.y * 64;
    const int bn = blockIdx.x * 64;      // n-tile; %8 = XCD -> W slice L2-hot

    const int srow = tid >> 3;           // 0..63
    const int c8   = (tid & 7) * 8;      // 0..56

    const signed char* wg = Wp + (size_t)(bn + srow) * KP + c8;  // rows padded

    // ---- prefetch state (k-block 0) ----
    unsigned long long Wr[5];
#pragma unroll
    for (int p = 0; p < 5; ++p) Wr[p] = *(const unsigned long long*)(wg + p * planeW);

    float xv[8];
    unsigned long long Ar = 0;
    const float* xrow = nullptr;
    const signed char* ag = nullptr;
    if constexpr (NA == 5) {
        xrow = xsrc + (size_t)(bm + srow) * 784;
#pragma unroll
        for (int j = 0; j < 8; ++j) { int k = c8 + j; xv[j] = (k < 784) ? xrow[k] : 0.f; }
    } else {
        ag = Asp + (size_t)(bm + srow) * KP + c8;
        Ar = *(const unsigned long long*)ag;
    }

    int4v acc[2][5];
#pragma unroll
    for (int mi = 0; mi < 2; ++mi)
#pragma unroll
        for (int s = 0; s < 5; ++s) acc[mi][s] = (int4v){0, 0, 0, 0};

    for (int it = 0; it < NIT; ++it) {
        __syncthreads();
#pragma unroll
        for (int p = 0; p < 5; ++p)
            *(unsigned long long*)&Wld[(p * 64 + srow) * 80 + c8] = Wr[p];
        if constexpr (NA == 5) {
            unsigned pk[5][2] = {{0,0},{0,0},{0,0},{0,0},{0,0}};
#pragma unroll
            for (int j = 0; j < 8; ++j) {
                long long v = __double2ll_rn((double)xv[j] * XSCALE);
#pragma unroll
                for (int p = 0; p < 4; ++p) {
                    int dg = (int)(v & 255); if (dg > 127) dg -= 256;
                    pk[p][j >> 2] |= (unsigned)(dg & 255) << ((j & 3) * 8);
                    v = (v - dg) >> 8;
                }
                pk[4][j >> 2] |= (unsigned)((int)v & 255) << ((j & 3) * 8);
            }
#pragma unroll
            for (int p = 0; p < 5; ++p) {
                unsigned long long u = (unsigned long long)pk[p][0]
                                     | ((unsigned long long)pk[p][1] << 32);
                *(unsigned long long*)&Ald[(p * 64 + srow) * 80 + c8] = u;
            }
        } else {
            *(unsigned long long*)&Ald[srow * 80 + c8] = Ar;
        }
        __syncthreads();

        if (it + 1 < NIT) {               // prefetch next k-block during compute
            int kb = (it + 1) * 64;
#pragma unroll
            for (int p = 0; p < 5; ++p)
                Wr[p] = *(const unsigned long long*)(wg + kb + p * planeW);
            if constexpr (NA == 5) {
#pragma unroll
                for (int j = 0; j < 8; ++j) {
                    int k = kb + c8 + j;
                    xv[j] = (k < 784) ? xrow[k] : 0.f;
                }
            } else {
                Ar = *(const unsigned long long*)(ag + kb);
            }
        }

        // ---- fragments + MFMA (A,B share k-map: any HW k-permutation cancels) ----
        int4v bq[5];
#pragma unroll
        for (int q = 0; q < 5; ++q)
            bq[q] = *(const int4v*)&Wld[(q * 64 + wno + fr) * 80 + 16 * g];
#pragma unroll
        for (int mi = 0; mi < 2; ++mi) {
            if constexpr (NA == 5) {
                int4v af[5];
#pragma unroll
                for (int p = 0; p < 5; ++p)
                    af[p] = *(const int4v*)&Ald[(p * 64 + wmo + mi * 16 + fr) * 80 + 16 * g];
#pragma unroll
                for (int q = 0; q < 5; ++q)
#pragma unroll
                    for (int p = 0; p < 5; ++p)
                        if (p + q >= 4)
                            acc[mi][p + q - 4] = __builtin_amdgcn_mfma_i32_16x16x64_i8(
                                af[p], bq[q], acc[mi][p + q - 4], 0, 0, 0);
            } else {
                int4v a0 = *(const int4v*)&Ald[(wmo + mi * 16 + fr) * 80 + 16 * g];
#pragma unroll
                for (int q = 0; q < 5; ++q)
                    acc[mi][q] = __builtin_amdgcn_mfma_i32_16x16x64_i8(
                        a0, bq[q], acc[mi][q], 0, 0, 0);
            }
        }
    }

    // ---- epilogue: exact fp64 reconstruction; C/D: col=l&15, row=4*(l>>4)+r ----
    const int col = bn + wno + fr;
    if (col < CS) {
#pragma unroll
        for (int mi = 0; mi < 2; ++mi)
#pragma unroll
            for (int r = 0; r < 4; ++r) {
                int row = bm + wmo + mi * 16 + 4 * g + r;
                double v = (double)acc[mi][4][r];
                v = v * 256.0 + (double)acc[mi][3][r];
                v = v * 256.0 + (double)acc[mi][2][r];
                v = v * 256.0 + (double)acc[mi][1][r];
                v = v * 256.0 + (double)acc[mi][0][r];
                curout[(size_t)row * CS + col] = v * (NA == 5 ? 0x1p-44 : 0x1p-40);
            }
    }
}

// ---- elementwise leaky-IF over a chunk: one thread per neuron, t in regs ----
__global__ __launch_bounds__(256)
void if_update(const double* __restrict__ cur, const float* __restrict__ bias,
               double* __restrict__ mw, float* __restrict__ spk,
               float* __restrict__ mem, signed char* __restrict__ spk_i8,
               int N, int first)
{
    int idx = blockIdx.x * blockDim.x + threadIdx.x;
    if (idx >= 512 * N) return;
    int row = idx / N, col = idx - row * N;
    double mp = first ? 0.0 : mw[idx];
    double bs = (double)bias[col];
#pragma unroll 2
    for (int t = 0; t < TC; ++t) {
        double c   = cur[((size_t)t * 512 + row) * 1024 + col] + bs;
        double rst = (mp > 1.0) ? 1.0 : 0.0;
        double mn  = 0.9 * mp + c - rst;
        size_t o   = ((size_t)t * 512 + row) * N + col;
        spk[o] = (mn > 1.0) ? 1.0f : 0.0f;
        mem[o] = (float)mn;
        if (spk_i8)
            spk_i8[((size_t)t * 512 + row) * 1024 + col] = (signed char)((mn > 1.0) ? 1 : 0);
        mp = mn;
    }
    mw[idx] = mp;
}

// ---- layer-3 IF chain: 5120 neurons, all 50 t in registers ----
__global__ __launch_bounds__(256)
void if3_kernel(const double* __restrict__ cur3, const float* __restrict__ bias,
                float* __restrict__ spk3, float* __restrict__ mem3)
{
    int idx = blockIdx.x * blockDim.x + threadIdx.x;
    if (idx >= 5120) return;
    int brow = idx / 10, col = idx - brow * 10;
    double bs = (double)bias[col];
    double mp = 0.0;
    for (int t = 0; t < 50; ++t) {
        double c   = cur3[((size_t)t * 512 + brow) * 16 + col] + bs;
        double rst = (mp > 1.0) ? 1.0 : 0.0;
        double mn  = 0.9 * mp + c - rst;
        size_t o   = (size_t)t * 5120 + (size_t)brow * 10 + col;
        spk3[o] = (mn > 1.0) ? 1.0f : 0.0f;
        mem3[o] = (float)mn;
        mp = mn;
    }
}

extern "C" void kernel_launch(void* const* d_in, const int* in_sizes, int n_in,
                              void* d_out, int out_size, void* d_ws, size_t ws_size,
                              hipStream_t stream)
{
    const float* x  = (const float*)d_in[0];
    const float* W0 = (const float*)d_in[1];
    const float* b0 = (const float*)d_in[2];
    const float* W1 = (const float*)d_in[3];
    const float* b1 = (const float*)d_in[4];
    const float* W2 = (const float*)d_in[5];
    const float* b2 = (const float*)d_in[6];
    const float* W3 = (const float*)d_in[7];
    const float* b3 = (const float*)d_in[8];
    float* out = (float*)d_out;

    const int T = 50;
    const size_t LNH = (size_t)512 * 1000;
    const size_t LNO = (size_t)512 * 10;

    float* spk0 = out;
    float* spk1 = spk0 + (size_t)T * LNH;
    float* spk2 = spk1 + (size_t)T * LNH;
    float* spk3 = spk2 + (size_t)T * LNH;
    float* mem0 = spk3 + (size_t)T * LNO;
    float* mem1 = mem0 + (size_t)T * LNH;
    float* mem2 = mem1 + (size_t)T * LNH;
    float* mem3 = mem2 + (size_t)T * LNH;

    // ---- workspace layout (fp64 first, then i8) ----
    double* cur = (double*)d_ws;                          // 5120*1024*8 = 41.9 MB (cur3 reuses)
    double* mw0 = cur + (size_t)5120 * 1024;
    double* mw1 = mw0 + LNH;
    double* mw2 = mw1 + LNH;                              // mw3 not needed
    signed char* W0d = (signed char*)(mw2 + LNH);         // 5*1024*832
    signed char* W1d = W0d + (size_t)5 * 1024 * 832;      // 5*1024*1024
    signed char* W2d = W1d + (size_t)5 * 1024 * 1024;
    signed char* W3d = W2d + (size_t)5 * 1024 * 1024;     // 5*64*1024
    signed char* sp0 = W3d + (size_t)5 * 64 * 1024;       // chunk: 5120*1024
    signed char* sp1 = sp0 + (size_t)5120 * 1024;         // chunk: 5120*1024
    signed char* sp2 = sp1 + (size_t)5120 * 1024;         // FULL T: 25600*1024

    // zero spike buffers once (K-tail cols 1000..1023 must stay 0)
    hipMemsetAsync(sp0, 0, (size_t)2 * 5120 * 1024 + (size_t)25600 * 1024, stream);

    // W digit splits
    wsplit_i8<<<(1024 * 832  + 255) / 256, 256, 0, stream>>>(W0, W0d, 1000, 1024, 784,  832);
    wsplit_i8<<<(1024 * 1024 + 255) / 256, 256, 0, stream>>>(W1, W1d, 1000, 1024, 1000, 1024);
    wsplit_i8<<<(1024 * 1024 + 255) / 256, 256, 0, stream>>>(W2, W2d, 1000, 1024, 1000, 1024);
    wsplit_i8<<<(64 * 1024   + 255) / 256, 256, 0, stream>>>(W3, W3d, 10,   64,   1000, 1024);

    const size_t plW0 = (size_t)1024 * 832;
    const size_t plWH = (size_t)1024 * 1024;
    const size_t plW3 = (size_t)64 * 1024;

    dim3 blk(512);
    dim3 gH(16, 80);     // 16 n-tiles x 80 m-tiles (M=5120)
    dim3 g3(1, 400);     // L3: M=25600, one 64-col n-tile

    for (int c = 0; c < T / TC; ++c) {
        const int t0 = c * TC;
        const int first = (c == 0);

        gemm_i8<5, 832, 1024><<<gH, blk, 0, stream>>>(
            x + (size_t)t0 * 512 * 784, nullptr, W0d, plW0, cur);
        if_update<<<2000, 256, 0, stream>>>(cur, b0, mw0,
            spk0 + (size_t)t0 * LNH, mem0 + (size_t)t0 * LNH, sp0, 1000, first);

        gemm_i8<1, 1024, 1024><<<gH, blk, 0, stream>>>(
            nullptr, sp0, W1d, plWH, cur);
        if_update<<<2000, 256, 0, stream>>>(cur, b1, mw1,
            spk1 + (size_t)t0 * LNH, mem1 + (size_t)t0 * LNH, sp1, 1000, first);

        gemm_i8<1, 1024, 1024><<<gH, blk, 0, stream>>>(
            nullptr, sp1, W2d, plWH, cur);
        if_update<<<2000, 256, 0, stream>>>(cur, b2, mw2,
            spk2 + (size_t)t0 * LNH, mem2 + (size_t)t0 * LNH,
            sp2 + (size_t)t0 * 512 * 1024, 1000, first);
    }

    // layer 3: one batched GEMM over all 50 t (M=25600), then tiny IF chain
    gemm_i8<1, 1024, 16><<<g3, blk, 0, stream>>>(nullptr, sp2, W3d, plW3, cur);
    if3_kernel<<<20, 256, 0, stream>>>(cur, b3, spk3, mem3);
}

// Round 11
// 1181.564 us; speedup vs baseline: 1.4614x; 1.2995x over previous
//
#include <hip/hip_runtime.h>

// SNN forward, exact fixed-point int8 MFMA on 32x32x32 matrix cores.
// Decoupled structure (round-8 proven): per TC=10-step chunk,
//   batched GEMM (M=5120) -> exact fp64 cur -> elementwise leaky-IF.
// Numerics identical to rounds 4-10 (all passed): spikes exact in i8; W = 5
// balanced base-256 digits of round(w*2^40); x digitized to round(x*2^36)
// (digit pairs p+q>=4); i32 MFMA accumulation exact; cur fp64 (<2^53 exact).
// 32x32x32 i8 MFMA: 2x arithmetic intensity per fragment byte vs 16x16x64
// (65536 ops / 2KB operands) and higher ceiling (4404 TOPS, m55).
// C/D layout (m74/m101, dtype-indep m121-128): col=l&31, row=(reg&3)+8*(reg>>2)+4*(l>>5).
// A/B fragments: 16B per lane at k-offset 16*(l>>5) (+32 per k2) -- A and B use
// the identical lane->k map, so any HW k-permutation cancels in the dot product.

typedef int int4v  __attribute__((ext_vector_type(4)));
typedef int int16v __attribute__((ext_vector_type(16)));

#define XSCALE 68719476736.0      // 2^36
#define WSCALE 1099511627776.0    // 2^40
#define TC 10

// ---- W digit split: fp32 [Nreal][K] -> 5 planes [Npad][Kpad], zero-padded ----
__global__ void wsplit_i8(const float* __restrict__ W, signed char* __restrict__ out,
                          int Nreal, int Npad, int K, int Kpad)
{
    int idx = blockIdx.x * blockDim.x + threadIdx.x;
    int total = Npad * Kpad;
    if (idx >= total) return;
    int n = idx / Kpad, k = idx - n * Kpad;
    long long v = 0;
    if (n < Nreal && k < K) v = __double2ll_rn((double)W[(size_t)n * K + k] * WSCALE);
    size_t plane = (size_t)total;
#pragma unroll
    for (int p = 0; p < 4; ++p) {
        int d = (int)(v & 255); if (d > 127) d -= 256;
        out[p * plane + idx] = (signed char)d;
        v = (v - d) >> 8;
    }
    out[4 * plane + idx] = (signed char)v;
}

// ---- x chunk digitize: [TC*512][784] fp32 -> 5 planes [5120][832] ----
__global__ void xsplit_chunk(const float* __restrict__ x, signed char* __restrict__ out)
{
    int idx = blockIdx.x * blockDim.x + threadIdx.x;
    if (idx >= 5120 * 832) return;
    int row = idx / 832, k = idx - row * 832;
    long long v = 0;
    if (k < 784) v = __double2ll_rn((double)x[(size_t)row * 784 + k] * XSCALE);
    const size_t plane = (size_t)5120 * 832;
    signed char* o = out + idx;
#pragma unroll
    for (int p = 0; p < 4; ++p) {
        int d = (int)(v & 255); if (d > 127) d -= 256;
        o[p * plane] = (signed char)d;
        v = (v - d) >> 8;
    }
    o[4 * plane] = (signed char)v;
}

// ---- GEMM: cur[M][CS] (fp64) = A @ W^T, exact, 32x32x32 i8 MFMA ----
// NA=5: A = x digit planes (L0, triangular pairs p+q>=4). NA=1: spike plane.
// Block 256 thr = 4 waves (2M x 2N); block tile 64x64; wave tile 32x32.
template<int NA, int KP, int CS>
__global__ __launch_bounds__(256)
void gemm32(const signed char* __restrict__ Ap, size_t planeA,
            const signed char* __restrict__ Wp, size_t planeW,
            double* __restrict__ curout)
{
    __shared__ __align__(16) signed char Wld[5 * 64 * 80];    // 25.6 KB
    __shared__ __align__(16) signed char Ald[NA * 64 * 80];
    constexpr int NIT = KP / 64;

    const int tid = threadIdx.x;
    const int l   = tid & 63;
    const int w   = tid >> 6;           // 0..3
    const int wm  = (w & 1) * 32;
    const int wn  = (w >> 1) * 32;
    const int r32 = l & 31;
    const int h   = l >> 5;             // k-half select

    const int bm = blockIdx.y * 64;
    const int bn = blockIdx.x * 64;

    const int srow = tid >> 2;          // 0..63
    const int sc   = (tid & 3) * 16;    // 0/16/32/48

    const signed char* ag = Ap + (size_t)(bm + srow) * KP + sc;
    const signed char* wg = Wp + (size_t)(bn + srow) * KP + sc;   // rows zero-padded

    // prefetch k-block 0
    int4v Ar[NA], Wr[5];
#pragma unroll
    for (int p = 0; p < 5; ++p)  Wr[p] = *(const int4v*)(wg + p * planeW);
#pragma unroll
    for (int p = 0; p < NA; ++p) Ar[p] = *(const int4v*)(ag + p * planeA);

    int16v acc[5];
#pragma unroll
    for (int s = 0; s < 5; ++s)
#pragma unroll
        for (int r = 0; r < 16; ++r) acc[s][r] = 0;

    for (int it = 0; it < NIT; ++it) {
        __syncthreads();
#pragma unroll
        for (int p = 0; p < 5; ++p)
            *(int4v*)&Wld[(p * 64 + srow) * 80 + sc] = Wr[p];
#pragma unroll
        for (int p = 0; p < NA; ++p)
            *(int4v*)&Ald[(p * 64 + srow) * 80 + sc] = Ar[p];
        __syncthreads();

        if (it + 1 < NIT) {             // prefetch next k-block under compute
            int kb = (it + 1) * 64;
#pragma unroll
            for (int p = 0; p < 5; ++p)
                Wr[p] = *(const int4v*)(wg + kb + p * planeW);
#pragma unroll
            for (int p = 0; p < NA; ++p)
                Ar[p] = *(const int4v*)(ag + kb + p * planeA);
        }

#pragma unroll
        for (int k2 = 0; k2 < 2; ++k2) {
            const int off = k2 * 32 + 16 * h;
            if constexpr (NA == 5) {
                int4v af[5], bq[5];
#pragma unroll
                for (int p = 0; p < 5; ++p)
                    af[p] = *(const int4v*)&Ald[(p * 64 + wm + r32) * 80 + off];
#pragma unroll
                for (int q = 0; q < 5; ++q)
                    bq[q] = *(const int4v*)&Wld[(q * 64 + wn + r32) * 80 + off];
#pragma unroll
                for (int q = 0; q < 5; ++q)
#pragma unroll
                    for (int p = 0; p < 5; ++p)
                        if (p + q >= 4)
                            acc[p + q - 4] = __builtin_amdgcn_mfma_i32_32x32x32_i8(
                                af[p], bq[q], acc[p + q - 4], 0, 0, 0);
            } else {
                int4v a0 = *(const int4v*)&Ald[(wm + r32) * 80 + off];
#pragma unroll
                for (int q = 0; q < 5; ++q) {
                    int4v bq = *(const int4v*)&Wld[(q * 64 + wn + r32) * 80 + off];
                    acc[q] = __builtin_amdgcn_mfma_i32_32x32x32_i8(a0, bq, acc[q], 0, 0, 0);
                }
            }
        }
    }

    // epilogue: exact fp64 reconstruction
    const int col = bn + wn + r32;
    if (col < CS) {
#pragma unroll
        for (int reg = 0; reg < 16; ++reg) {
            int row = bm + wm + (reg & 3) + 8 * (reg >> 2) + 4 * h;
            double v = (double)acc[4][reg];
            v = v * 256.0 + (double)acc[3][reg];
            v = v * 256.0 + (double)acc[2][reg];
            v = v * 256.0 + (double)acc[1][reg];
            v = v * 256.0 + (double)acc[0][reg];
            curout[(size_t)row * CS + col] = v * (NA == 5 ? 0x1p-44 : 0x1p-40);
        }
    }
}

// ---- elementwise leaky-IF over a chunk: one thread per neuron, t in regs ----
__global__ __launch_bounds__(256)
void if_update(const double* __restrict__ cur, const float* __restrict__ bias,
               double* __restrict__ mw, float* __restrict__ spk,
               float* __restrict__ mem, signed char* __restrict__ spk_i8,
               int N, int first)
{
    int idx = blockIdx.x * blockDim.x + threadIdx.x;
    if (idx >= 512 * N) return;
    int row = idx / N, col = idx - row * N;
    double mp = first ? 0.0 : mw[idx];
    double bs = (double)bias[col];
#pragma unroll 2
    for (int t = 0; t < TC; ++t) {
        double c   = cur[((size_t)t * 512 + row) * 1024 + col] + bs;
        double rst = (mp > 1.0) ? 1.0 : 0.0;
        double mn  = 0.9 * mp + c - rst;
        size_t o   = ((size_t)t * 512 + row) * N + col;
        spk[o] = (mn > 1.0) ? 1.0f : 0.0f;
        mem[o] = (float)mn;
        if (spk_i8)
            spk_i8[((size_t)t * 512 + row) * 1024 + col] = (signed char)((mn > 1.0) ? 1 : 0);
        mp = mn;
    }
    mw[idx] = mp;
}

// ---- layer-3 IF chain: 5120 neurons, all 50 t in registers ----
__global__ __launch_bounds__(256)
void if3_kernel(const double* __restrict__ cur3, const float* __restrict__ bias,
                float* __restrict__ spk3, float* __restrict__ mem3)
{
    int idx = blockIdx.x * blockDim.x + threadIdx.x;
    if (idx >= 5120) return;
    int brow = idx / 10, col = idx - brow * 10;
    double bs = (double)bias[col];
    double mp = 0.0;
    for (int t = 0; t < 50; ++t) {
        double c   = cur3[((size_t)t * 512 + brow) * 16 + col] + bs;
        double rst = (mp > 1.0) ? 1.0 : 0.0;
        double mn  = 0.9 * mp + c - rst;
        size_t o   = (size_t)t * 5120 + (size_t)brow * 10 + col;
        spk3[o] = (mn > 1.0) ? 1.0f : 0.0f;
        mem3[o] = (float)mn;
        mp = mn;
    }
}

extern "C" void kernel_launch(void* const* d_in, const int* in_sizes, int n_in,
                              void* d_out, int out_size, void* d_ws, size_t ws_size,
                              hipStream_t stream)
{
    const float* x  = (const float*)d_in[0];
    const float* W0 = (const float*)d_in[1];
    const float* b0 = (const float*)d_in[2];
    const float* W1 = (const float*)d_in[3];
    const float* b1 = (const float*)d_in[4];
    const float* W2 = (const float*)d_in[5];
    const float* b2 = (const float*)d_in[6];
    const float* W3 = (const float*)d_in[7];
    const float* b3 = (const float*)d_in[8];
    float* out = (float*)d_out;

    const int T = 50;
    const size_t LNH = (size_t)512 * 1000;
    const size_t LNO = (size_t)512 * 10;

    float* spk0 = out;
    float* spk1 = spk0 + (size_t)T * LNH;
    float* spk2 = spk1 + (size_t)T * LNH;
    float* spk3 = spk2 + (size_t)T * LNH;
    float* mem0 = spk3 + (size_t)T * LNO;
    float* mem1 = mem0 + (size_t)T * LNH;
    float* mem2 = mem1 + (size_t)T * LNH;
    float* mem3 = mem2 + (size_t)T * LNH;

    // ---- workspace layout (fp64 first, then i8) ----
    double* cur = (double*)d_ws;                          // 5120*1024*8 = 41.9 MB
    double* mw0 = cur + (size_t)5120 * 1024;
    double* mw1 = mw0 + LNH;
    double* mw2 = mw1 + LNH;
    signed char* W0d = (signed char*)(mw2 + LNH);         // 5*1024*832
    signed char* W1d = W0d + (size_t)5 * 1024 * 832;      // 5*1024*1024
    signed char* W2d = W1d + (size_t)5 * 1024 * 1024;
    signed char* W3d = W2d + (size_t)5 * 1024 * 1024;     // 5*64*1024
    signed char* xsb = W3d + (size_t)5 * 64 * 1024;       // 5*5120*832 = 21.3 MB
    signed char* sp0 = xsb + (size_t)5 * 5120 * 832;      // chunk: 5120*1024
    signed char* sp1 = sp0 + (size_t)5120 * 1024;         // chunk: 5120*1024
    signed char* sp2 = sp1 + (size_t)5120 * 1024;         // full T: 25600*1024

    // zero spike buffers once (K-tail cols 1000..1023 must stay 0)
    hipMemsetAsync(sp0, 0, (size_t)2 * 5120 * 1024 + (size_t)25600 * 1024, stream);

    // W digit splits
    wsplit_i8<<<(1024 * 832  + 255) / 256, 256, 0, stream>>>(W0, W0d, 1000, 1024, 784,  832);
    wsplit_i8<<<(1024 * 1024 + 255) / 256, 256, 0, stream>>>(W1, W1d, 1000, 1024, 1000, 1024);
    wsplit_i8<<<(1024 * 1024 + 255) / 256, 256, 0, stream>>>(W2, W2d, 1000, 1024, 1000, 1024);
    wsplit_i8<<<(64 * 1024   + 255) / 256, 256, 0, stream>>>(W3, W3d, 10,   64,   1000, 1024);

    const size_t plA0 = (size_t)5120 * 832;
    const size_t plW0 = (size_t)1024 * 832;
    const size_t plWH = (size_t)1024 * 1024;
    const size_t plW3 = (size_t)64 * 1024;

    dim3 blk(256);
    dim3 gH(16, 80);     // 16 n-tiles x 80 m-tiles (M=5120, 64x64 tiles)
    dim3 g3(1, 400);     // L3: M=25600

    for (int c = 0; c < T / TC; ++c) {
        const int t0 = c * TC;
        const int first = (c == 0);

        xsplit_chunk<<<(5120 * 832 + 255) / 256, 256, 0, stream>>>(
            x + (size_t)t0 * 512 * 784, xsb);

        gemm32<5, 832, 1024><<<gH, blk, 0, stream>>>(xsb, plA0, W0d, plW0, cur);
        if_update<<<2000, 256, 0, stream>>>(cur, b0, mw0,
            spk0 + (size_t)t0 * LNH, mem0 + (size_t)t0 * LNH, sp0, 1000, first);

        gemm32<1, 1024, 1024><<<gH, blk, 0, stream>>>(sp0, 0, W1d, plWH, cur);
        if_update<<<2000, 256, 0, stream>>>(cur, b1, mw1,
            spk1 + (size_t)t0 * LNH, mem1 + (size_t)t0 * LNH, sp1, 1000, first);

        gemm32<1, 1024, 1024><<<gH, blk, 0, stream>>>(sp1, 0, W2d, plWH, cur);
        if_update<<<2000, 256, 0, stream>>>(cur, b2, mw2,
            spk2 + (size_t)t0 * LNH, mem2 + (size_t)t0 * LNH,
            sp2 + (size_t)t0 * 512 * 1024, 1000, first);
    }

    // layer 3: one batched GEMM over all 50 t (M=25600), then tiny IF chain
    gemm32<1, 1024, 16><<<g3, blk, 0, stream>>>(sp2, 0, W3d, plW3, cur);
    if3_kernel<<<20, 256, 0, stream>>>(cur, b3, spk3, mem3);
}

// Round 12
// 1101.933 us; speedup vs baseline: 1.5670x; 1.0723x over previous
//
#include <hip/hip_runtime.h>

// SNN forward, exact fixed-point int8 MFMA on 32x32x32 matrix cores.
// Decoupled structure (round-8/11 proven): per TC=10-step chunk,
//   batched GEMM (M=5120) -> exact fp64 cur -> elementwise leaky-IF.
// This round: LDS-BW-optimized wide GEMM for spike layers (wave tile 64x32,
// Mf=2 shares the 5 B-plane reads across 2 m-fragments: 0.7KB LDS reads/MFMA
// vs 1.2 before), + 2-col vectorized if_update.
// Numerics identical to rounds 4-11 (all passed): spikes exact in i8; W = 5
// balanced base-256 digits of round(w*2^40); x digitized to round(x*2^36)
// (digit pairs p+q>=4); i32 MFMA accumulation exact; cur fp64 (<2^53 exact).
// 32x32x32 C/D layout (m74/m101): col=l&31, row=(reg&3)+8*(reg>>2)+4*(l>>5).
// A/B share the identical lane->k map, so any HW k-permutation cancels.

typedef int int4v  __attribute__((ext_vector_type(4)));
typedef int int16v __attribute__((ext_vector_type(16)));

#define XSCALE 68719476736.0      // 2^36
#define WSCALE 1099511627776.0    // 2^40
#define TC 10

// ---- W digit split: fp32 [Nreal][K] -> 5 planes [Npad][Kpad], zero-padded ----
__global__ void wsplit_i8(const float* __restrict__ W, signed char* __restrict__ out,
                          int Nreal, int Npad, int K, int Kpad)
{
    int idx = blockIdx.x * blockDim.x + threadIdx.x;
    int total = Npad * Kpad;
    if (idx >= total) return;
    int n = idx / Kpad, k = idx - n * Kpad;
    long long v = 0;
    if (n < Nreal && k < K) v = __double2ll_rn((double)W[(size_t)n * K + k] * WSCALE);
    size_t plane = (size_t)total;
#pragma unroll
    for (int p = 0; p < 4; ++p) {
        int d = (int)(v & 255); if (d > 127) d -= 256;
        out[p * plane + idx] = (signed char)d;
        v = (v - d) >> 8;
    }
    out[4 * plane + idx] = (signed char)v;
}

// ---- x chunk digitize: [TC*512][784] fp32 -> 5 planes [5120][832] ----
__global__ void xsplit_chunk(const float* __restrict__ x, signed char* __restrict__ out)
{
    int idx = blockIdx.x * blockDim.x + threadIdx.x;
    if (idx >= 5120 * 832) return;
    int row = idx / 832, k = idx - row * 832;
    long long v = 0;
    if (k < 784) v = __double2ll_rn((double)x[(size_t)row * 784 + k] * XSCALE);
    const size_t plane = (size_t)5120 * 832;
    signed char* o = out + idx;
#pragma unroll
    for (int p = 0; p < 4; ++p) {
        int d = (int)(v & 255); if (d > 127) d -= 256;
        o[p * plane] = (signed char)d;
        v = (v - d) >> 8;
    }
    o[4 * plane] = (signed char)v;
}

// ---- L0/L3 GEMM (round-11 proven): block 64x64, 4 waves 2x2, wave 32x32 ----
template<int NA, int KP, int CS>
__global__ __launch_bounds__(256)
void gemm32(const signed char* __restrict__ Ap, size_t planeA,
            const signed char* __restrict__ Wp, size_t planeW,
            double* __restrict__ curout)
{
    __shared__ __align__(16) signed char Wld[5 * 64 * 80];
    __shared__ __align__(16) signed char Ald[NA * 64 * 80];
    constexpr int NIT = KP / 64;

    const int tid = threadIdx.x;
    const int l   = tid & 63;
    const int w   = tid >> 6;
    const int wm  = (w & 1) * 32;
    const int wn  = (w >> 1) * 32;
    const int r32 = l & 31;
    const int h   = l >> 5;

    const int bm = blockIdx.y * 64;
    const int bn = blockIdx.x * 64;

    const int srow = tid >> 2;
    const int sc   = (tid & 3) * 16;

    const signed char* ag = Ap + (size_t)(bm + srow) * KP + sc;
    const signed char* wg = Wp + (size_t)(bn + srow) * KP + sc;

    int4v Ar[NA], Wr[5];
#pragma unroll
    for (int p = 0; p < 5; ++p)  Wr[p] = *(const int4v*)(wg + p * planeW);
#pragma unroll
    for (int p = 0; p < NA; ++p) Ar[p] = *(const int4v*)(ag + p * planeA);

    int16v acc[5];
#pragma unroll
    for (int s = 0; s < 5; ++s)
#pragma unroll
        for (int r = 0; r < 16; ++r) acc[s][r] = 0;

    for (int it = 0; it < NIT; ++it) {
        __syncthreads();
#pragma unroll
        for (int p = 0; p < 5; ++p)
            *(int4v*)&Wld[(p * 64 + srow) * 80 + sc] = Wr[p];
#pragma unroll
        for (int p = 0; p < NA; ++p)
            *(int4v*)&Ald[(p * 64 + srow) * 80 + sc] = Ar[p];
        __syncthreads();

        if (it + 1 < NIT) {
            int kb = (it + 1) * 64;
#pragma unroll
            for (int p = 0; p < 5; ++p)
                Wr[p] = *(const int4v*)(wg + kb + p * planeW);
#pragma unroll
            for (int p = 0; p < NA; ++p)
                Ar[p] = *(const int4v*)(ag + kb + p * planeA);
        }

#pragma unroll
        for (int k2 = 0; k2 < 2; ++k2) {
            const int off = k2 * 32 + 16 * h;
            if constexpr (NA == 5) {
                int4v af[5], bq[5];
#pragma unroll
                for (int p = 0; p < 5; ++p)
                    af[p] = *(const int4v*)&Ald[(p * 64 + wm + r32) * 80 + off];
#pragma unroll
                for (int q = 0; q < 5; ++q)
                    bq[q] = *(const int4v*)&Wld[(q * 64 + wn + r32) * 80 + off];
#pragma unroll
                for (int q = 0; q < 5; ++q)
#pragma unroll
                    for (int p = 0; p < 5; ++p)
                        if (p + q >= 4)
                            acc[p + q - 4] = __builtin_amdgcn_mfma_i32_32x32x32_i8(
                                af[p], bq[q], acc[p + q - 4], 0, 0, 0);
            } else {
                int4v a0 = *(const int4v*)&Ald[(wm + r32) * 80 + off];
#pragma unroll
                for (int q = 0; q < 5; ++q) {
                    int4v bq = *(const int4v*)&Wld[(q * 64 + wn + r32) * 80 + off];
                    acc[q] = __builtin_amdgcn_mfma_i32_32x32x32_i8(a0, bq, acc[q], 0, 0, 0);
                }
            }
        }
    }

    const int col = bn + wn + r32;
    if (col < CS) {
#pragma unroll
        for (int reg = 0; reg < 16; ++reg) {
            int row = bm + wm + (reg & 3) + 8 * (reg >> 2) + 4 * h;
            double v = (double)acc[4][reg];
            v = v * 256.0 + (double)acc[3][reg];
            v = v * 256.0 + (double)acc[2][reg];
            v = v * 256.0 + (double)acc[1][reg];
            v = v * 256.0 + (double)acc[0][reg];
            curout[(size_t)row * CS + col] = v * (NA == 5 ? 0x1p-44 : 0x1p-40);
        }
    }
}

// ---- wide spike-layer GEMM: block 128x64, 4 waves 2x2, wave 64x32 (Mf=2) ----
// LDS reads (2 af + 5 bq) per 10 MFMAs; acc = 160 VGPR.
template<int KP>
__global__ __launch_bounds__(256)
void gemm32w(const signed char* __restrict__ Asp,
             const signed char* __restrict__ Wp, size_t planeW,
             double* __restrict__ curout)
{
    __shared__ __align__(16) signed char Wld[5 * 64 * 80];   // 25.6 KB
    __shared__ __align__(16) signed char Ald[128 * 80];      // 10.2 KB
    constexpr int NIT = KP / 64;

    const int tid = threadIdx.x;
    const int l   = tid & 63;
    const int w   = tid >> 6;           // 0..3
    const int wm  = (w & 1) * 64;       // wave m offset: 0/64
    const int wn  = (w >> 1) * 32;      // wave n offset: 0/32
    const int r32 = l & 31;
    const int h   = l >> 5;

    const int bm = blockIdx.y * 128;
    const int bn = blockIdx.x * 64;

    const int srA = tid >> 1;           // 0..127
    const int scA = (tid & 1) * 32;     // 0/32 (two b128 each)
    const int srW = tid >> 2;           // 0..63
    const int scW = (tid & 3) * 16;

    const signed char* ag = Asp + (size_t)(bm + srA) * KP + scA;
    const signed char* wg = Wp  + (size_t)(bn + srW) * KP + scW;

    int4v Ar0 = *(const int4v*)(ag);
    int4v Ar1 = *(const int4v*)(ag + 16);
    int4v Wr[5];
#pragma unroll
    for (int p = 0; p < 5; ++p) Wr[p] = *(const int4v*)(wg + p * planeW);

    int16v acc[2][5];
#pragma unroll
    for (int mi = 0; mi < 2; ++mi)
#pragma unroll
        for (int s = 0; s < 5; ++s)
#pragma unroll
            for (int r = 0; r < 16; ++r) acc[mi][s][r] = 0;

    for (int it = 0; it < NIT; ++it) {
        __syncthreads();
#pragma unroll
        for (int p = 0; p < 5; ++p)
            *(int4v*)&Wld[(p * 64 + srW) * 80 + scW] = Wr[p];
        *(int4v*)&Ald[srA * 80 + scA]      = Ar0;
        *(int4v*)&Ald[srA * 80 + scA + 16] = Ar1;
        __syncthreads();

        if (it + 1 < NIT) {
            int kb = (it + 1) * 64;
            Ar0 = *(const int4v*)(ag + kb);
            Ar1 = *(const int4v*)(ag + kb + 16);
#pragma unroll
            for (int p = 0; p < 5; ++p)
                Wr[p] = *(const int4v*)(wg + kb + p * planeW);
        }

#pragma unroll
        for (int k2 = 0; k2 < 2; ++k2) {
            const int off = k2 * 32 + 16 * h;
            int4v bq[5];
#pragma unroll
            for (int q = 0; q < 5; ++q)
                bq[q] = *(const int4v*)&Wld[(q * 64 + wn + r32) * 80 + off];
#pragma unroll
            for (int mi = 0; mi < 2; ++mi) {
                int4v a0 = *(const int4v*)&Ald[(wm + mi * 32 + r32) * 80 + off];
#pragma unroll
                for (int q = 0; q < 5; ++q)
                    acc[mi][q] = __builtin_amdgcn_mfma_i32_32x32x32_i8(
                        a0, bq[q], acc[mi][q], 0, 0, 0);
            }
        }
    }

    // epilogue: exact fp64 reconstruction (cols always < 1024 stride)
    const int col = bn + wn + r32;
#pragma unroll
    for (int mi = 0; mi < 2; ++mi)
#pragma unroll
        for (int reg = 0; reg < 16; ++reg) {
            int row = bm + wm + mi * 32 + (reg & 3) + 8 * (reg >> 2) + 4 * h;
            double v = (double)acc[mi][4][reg];
            v = v * 256.0 + (double)acc[mi][3][reg];
            v = v * 256.0 + (double)acc[mi][2][reg];
            v = v * 256.0 + (double)acc[mi][1][reg];
            v = v * 256.0 + (double)acc[mi][0][reg];
            curout[(size_t)row * 1024 + col] = v * 0x1p-40;
        }
}

// ---- leaky-IF over a chunk, 2 adjacent cols per thread (vectorized) ----
__global__ __launch_bounds__(256)
void if_update(const double* __restrict__ cur, const float* __restrict__ bias,
               double* __restrict__ mw, float* __restrict__ spk,
               float* __restrict__ mem, signed char* __restrict__ spk_i8,
               int first)
{
    int idx = blockIdx.x * blockDim.x + threadIdx.x;     // 512*500
    if (idx >= 512 * 500) return;
    int row = idx / 500, col = (idx - row * 500) * 2;
    double2 mp = first ? make_double2(0.0, 0.0)
                       : *(const double2*)&mw[(size_t)row * 1000 + col];
    double bs0 = (double)bias[col], bs1 = (double)bias[col + 1];
#pragma unroll 2
    for (int t = 0; t < TC; ++t) {
        double2 c = *(const double2*)&cur[((size_t)t * 512 + row) * 1024 + col];
        double rst0 = (mp.x > 1.0) ? 1.0 : 0.0;
        double rst1 = (mp.y > 1.0) ? 1.0 : 0.0;
        double mn0 = 0.9 * mp.x + (c.x + bs0) - rst0;
        double mn1 = 0.9 * mp.y + (c.y + bs1) - rst1;
        int s0 = (mn0 > 1.0) ? 1 : 0;
        int s1 = (mn1 > 1.0) ? 1 : 0;
        size_t o = ((size_t)t * 512 + row) * 1000 + col;
        *(float2*)&spk[o] = make_float2((float)s0, (float)s1);
        *(float2*)&mem[o] = make_float2((float)mn0, (float)mn1);
        *(short*)&spk_i8[((size_t)t * 512 + row) * 1024 + col] =
            (short)(s0 | (s1 << 8));
        mp.x = mn0; mp.y = mn1;
    }
    *(double2*)&mw[(size_t)row * 1000 + col] = mp;
}

// ---- layer-3 IF chain: 5120 neurons, all 50 t in registers ----
__global__ __launch_bounds__(256)
void if3_kernel(const double* __restrict__ cur3, const float* __restrict__ bias,
                float* __restrict__ spk3, float* __restrict__ mem3)
{
    int idx = blockIdx.x * blockDim.x + threadIdx.x;
    if (idx >= 5120) return;
    int brow = idx / 10, col = idx - brow * 10;
    double bs = (double)bias[col];
    double mp = 0.0;
    for (int t = 0; t < 50; ++t) {
        double c   = cur3[((size_t)t * 512 + brow) * 16 + col] + bs;
        double rst = (mp > 1.0) ? 1.0 : 0.0;
        double mn  = 0.9 * mp + c - rst;
        size_t o   = (size_t)t * 5120 + (size_t)brow * 10 + col;
        spk3[o] = (mn > 1.0) ? 1.0f : 0.0f;
        mem3[o] = (float)mn;
        mp = mn;
    }
}

extern "C" void kernel_launch(void* const* d_in, const int* in_sizes, int n_in,
                              void* d_out, int out_size, void* d_ws, size_t ws_size,
                              hipStream_t stream)
{
    const float* x  = (const float*)d_in[0];
    const float* W0 = (const float*)d_in[1];
    const float* b0 = (const float*)d_in[2];
    const float* W1 = (const float*)d_in[3];
    const float* b1 = (const float*)d_in[4];
    const float* W2 = (const float*)d_in[5];
    const float* b2 = (const float*)d_in[6];
    const float* W3 = (const float*)d_in[7];
    const float* b3 = (const float*)d_in[8];
    float* out = (float*)d_out;

    const int T = 50;
    const size_t LNH = (size_t)512 * 1000;
    const size_t LNO = (size_t)512 * 10;

    float* spk0 = out;
    float* spk1 = spk0 + (size_t)T * LNH;
    float* spk2 = spk1 + (size_t)T * LNH;
    float* spk3 = spk2 + (size_t)T * LNH;
    float* mem0 = spk3 + (size_t)T * LNO;
    float* mem1 = mem0 + (size_t)T * LNH;
    float* mem2 = mem1 + (size_t)T * LNH;
    float* mem3 = mem2 + (size_t)T * LNH;

    // ---- workspace layout (fp64 first, then i8) ----
    double* cur = (double*)d_ws;                          // 5120*1024*8 = 41.9 MB
    double* mw0 = cur + (size_t)5120 * 1024;
    double* mw1 = mw0 + LNH;
    double* mw2 = mw1 + LNH;
    signed char* W0d = (signed char*)(mw2 + LNH);         // 5*1024*832
    signed char* W1d = W0d + (size_t)5 * 1024 * 832;      // 5*1024*1024
    signed char* W2d = W1d + (size_t)5 * 1024 * 1024;
    signed char* W3d = W2d + (size_t)5 * 1024 * 1024;     // 5*64*1024
    signed char* xsb = W3d + (size_t)5 * 64 * 1024;       // 5*5120*832 = 21.3 MB
    signed char* sp0 = xsb + (size_t)5 * 5120 * 832;      // chunk: 5120*1024
    signed char* sp1 = sp0 + (size_t)5120 * 1024;         // chunk: 5120*1024
    signed char* sp2 = sp1 + (size_t)5120 * 1024;         // full T: 25600*1024

    // zero spike buffers once (K-tail cols 1000..1023 must stay 0)
    hipMemsetAsync(sp0, 0, (size_t)2 * 5120 * 1024 + (size_t)25600 * 1024, stream);

    // W digit splits
    wsplit_i8<<<(1024 * 832  + 255) / 256, 256, 0, stream>>>(W0, W0d, 1000, 1024, 784,  832);
    wsplit_i8<<<(1024 * 1024 + 255) / 256, 256, 0, stream>>>(W1, W1d, 1000, 1024, 1000, 1024);
    wsplit_i8<<<(1024 * 1024 + 255) / 256, 256, 0, stream>>>(W2, W2d, 1000, 1024, 1000, 1024);
    wsplit_i8<<<(64 * 1024   + 255) / 256, 256, 0, stream>>>(W3, W3d, 10,   64,   1000, 1024);

    const size_t plA0 = (size_t)5120 * 832;
    const size_t plW0 = (size_t)1024 * 832;
    const size_t plWH = (size_t)1024 * 1024;
    const size_t plW3 = (size_t)64 * 1024;

    dim3 blk(256);
    dim3 g0(16, 80);     // L0: 64x64 tiles
    dim3 gW(16, 40);     // L1/L2: 128x64 tiles (wide kernel)
    dim3 g3(1, 400);     // L3: M=25600, 64x64 tiles

    for (int c = 0; c < T / TC; ++c) {
        const int t0 = c * TC;
        const int first = (c == 0);

        xsplit_chunk<<<(5120 * 832 + 255) / 256, 256, 0, stream>>>(
            x + (size_t)t0 * 512 * 784, xsb);

        gemm32<5, 832, 1024><<<g0, blk, 0, stream>>>(xsb, plA0, W0d, plW0, cur);
        if_update<<<1000, 256, 0, stream>>>(cur, b0, mw0,
            spk0 + (size_t)t0 * LNH, mem0 + (size_t)t0 * LNH, sp0, first);

        gemm32w<1024><<<gW, blk, 0, stream>>>(sp0, W1d, plWH, cur);
        if_update<<<1000, 256, 0, stream>>>(cur, b1, mw1,
            spk1 + (size_t)t0 * LNH, mem1 + (size_t)t0 * LNH, sp1, first);

        gemm32w<1024><<<gW, blk, 0, stream>>>(sp1, W2d, plWH, cur);
        if_update<<<1000, 256, 0, stream>>>(cur, b2, mw2,
            spk2 + (size_t)t0 * LNH, mem2 + (size_t)t0 * LNH,
            sp2 + (size_t)t0 * 512 * 1024, first);
    }

    // layer 3: one batched GEMM over all 50 t (M=25600), then tiny IF chain
    gemm32<1, 1024, 16><<<g3, blk, 0, stream>>>(sp2, 0, W3d, plW3, cur);
    if3_kernel<<<20, 256, 0, stream>>>(cur, b3, spk3, mem3);
}

// Round 13
// 1059.777 us; speedup vs baseline: 1.6293x; 1.0398x over previous
//
#include <hip/hip_runtime.h>

// SNN forward, exact fixed-point int8 MFMA on 32x32x32 matrix cores.
// Full-T decoupled structure (ws ~2.4 GB per round-12 fillBuffer evidence):
//   per layer: ONE batched GEMM over all 50 timesteps (M=25600) -> exact fp64
//   cur -> ONE elementwise leaky-IF kernel (membrane state in registers across
//   all 50 steps -- never touches memory). 13 launches total.
// Numerics identical to rounds 4-12 (all passed): spikes exact in i8; W = 5
// balanced base-256 digits of round(w*2^40); x digitized to round(x*2^36)
// (digit pairs p+q>=4); i32 MFMA accumulation exact; cur fp64 (<2^53 exact).
// 32x32x32 C/D layout (m74/m101): col=l&31, row=(reg&3)+8*(reg>>2)+4*(l>>5).
// A/B share the identical lane->k map, so any HW k-permutation cancels.

typedef int int4v  __attribute__((ext_vector_type(4)));
typedef int int16v __attribute__((ext_vector_type(16)));

#define XSCALE 68719476736.0      // 2^36
#define WSCALE 1099511627776.0    // 2^40
#define MT 25600                  // 50 t x 512 batch rows

// ---- W digit split: fp32 [Nreal][K] -> 5 planes [Npad][Kpad], zero-padded ----
__global__ void wsplit_i8(const float* __restrict__ W, signed char* __restrict__ out,
                          int Nreal, int Npad, int K, int Kpad)
{
    int idx = blockIdx.x * blockDim.x + threadIdx.x;
    int total = Npad * Kpad;
    if (idx >= total) return;
    int n = idx / Kpad, k = idx - n * Kpad;
    long long v = 0;
    if (n < Nreal && k < K) v = __double2ll_rn((double)W[(size_t)n * K + k] * WSCALE);
    size_t plane = (size_t)total;
#pragma unroll
    for (int p = 0; p < 4; ++p) {
        int d = (int)(v & 255); if (d > 127) d -= 256;
        out[p * plane + idx] = (signed char)d;
        v = (v - d) >> 8;
    }
    out[4 * plane + idx] = (signed char)v;
}

// ---- x digitize (all 50 t): [25600][784] fp32 -> 5 planes [25600][832] ----
__global__ void xsplit_all(const float* __restrict__ x, signed char* __restrict__ out)
{
    int idx = blockIdx.x * blockDim.x + threadIdx.x;
    if (idx >= MT * 832) return;
    int row = idx / 832, k = idx - row * 832;
    long long v = 0;
    if (k < 784) v = __double2ll_rn((double)x[(size_t)row * 784 + k] * XSCALE);
    const size_t plane = (size_t)MT * 832;
    signed char* o = out + idx;
#pragma unroll
    for (int p = 0; p < 4; ++p) {
        int d = (int)(v & 255); if (d > 127) d -= 256;
        o[p * plane] = (signed char)d;
        v = (v - d) >> 8;
    }
    o[4 * plane] = (signed char)v;
}

// ---- L0/L3 GEMM: block 64x64, 4 waves 2x2, wave 32x32 ----
template<int NA, int KP, int CS>
__global__ __launch_bounds__(256)
void gemm32(const signed char* __restrict__ Ap, size_t planeA,
            const signed char* __restrict__ Wp, size_t planeW,
            double* __restrict__ curout)
{
    __shared__ __align__(16) signed char Wld[5 * 64 * 80];
    __shared__ __align__(16) signed char Ald[NA * 64 * 80];
    constexpr int NIT = KP / 64;

    const int tid = threadIdx.x;
    const int l   = tid & 63;
    const int w   = tid >> 6;
    const int wm  = (w & 1) * 32;
    const int wn  = (w >> 1) * 32;
    const int r32 = l & 31;
    const int h   = l >> 5;

    const int bm = blockIdx.y * 64;
    const int bn = blockIdx.x * 64;

    const int srow = tid >> 2;
    const int sc   = (tid & 3) * 16;

    const signed char* ag = Ap + (size_t)(bm + srow) * KP + sc;
    const signed char* wg = Wp + (size_t)(bn + srow) * KP + sc;

    int4v Ar[NA], Wr[5];
#pragma unroll
    for (int p = 0; p < 5; ++p)  Wr[p] = *(const int4v*)(wg + p * planeW);
#pragma unroll
    for (int p = 0; p < NA; ++p) Ar[p] = *(const int4v*)(ag + p * planeA);

    int16v acc[5];
#pragma unroll
    for (int s = 0; s < 5; ++s)
#pragma unroll
        for (int r = 0; r < 16; ++r) acc[s][r] = 0;

    for (int it = 0; it < NIT; ++it) {
        __syncthreads();
#pragma unroll
        for (int p = 0; p < 5; ++p)
            *(int4v*)&Wld[(p * 64 + srow) * 80 + sc] = Wr[p];
#pragma unroll
        for (int p = 0; p < NA; ++p)
            *(int4v*)&Ald[(p * 64 + srow) * 80 + sc] = Ar[p];
        __syncthreads();

        if (it + 1 < NIT) {
            int kb = (it + 1) * 64;
#pragma unroll
            for (int p = 0; p < 5; ++p)
                Wr[p] = *(const int4v*)(wg + kb + p * planeW);
#pragma unroll
            for (int p = 0; p < NA; ++p)
                Ar[p] = *(const int4v*)(ag + kb + p * planeA);
        }

#pragma unroll
        for (int k2 = 0; k2 < 2; ++k2) {
            const int off = k2 * 32 + 16 * h;
            if constexpr (NA == 5) {
                int4v af[5], bq[5];
#pragma unroll
                for (int p = 0; p < 5; ++p)
                    af[p] = *(const int4v*)&Ald[(p * 64 + wm + r32) * 80 + off];
#pragma unroll
                for (int q = 0; q < 5; ++q)
                    bq[q] = *(const int4v*)&Wld[(q * 64 + wn + r32) * 80 + off];
#pragma unroll
                for (int q = 0; q < 5; ++q)
#pragma unroll
                    for (int p = 0; p < 5; ++p)
                        if (p + q >= 4)
                            acc[p + q - 4] = __builtin_amdgcn_mfma_i32_32x32x32_i8(
                                af[p], bq[q], acc[p + q - 4], 0, 0, 0);
            } else {
                int4v a0 = *(const int4v*)&Ald[(wm + r32) * 80 + off];
#pragma unroll
                for (int q = 0; q < 5; ++q) {
                    int4v bq = *(const int4v*)&Wld[(q * 64 + wn + r32) * 80 + off];
                    acc[q] = __builtin_amdgcn_mfma_i32_32x32x32_i8(a0, bq, acc[q], 0, 0, 0);
                }
            }
        }
    }

    const int col = bn + wn + r32;
    if (col < CS) {
#pragma unroll
        for (int reg = 0; reg < 16; ++reg) {
            int row = bm + wm + (reg & 3) + 8 * (reg >> 2) + 4 * h;
            double v = (double)acc[4][reg];
            v = v * 256.0 + (double)acc[3][reg];
            v = v * 256.0 + (double)acc[2][reg];
            v = v * 256.0 + (double)acc[1][reg];
            v = v * 256.0 + (double)acc[0][reg];
            curout[(size_t)row * CS + col] = v * (NA == 5 ? 0x1p-44 : 0x1p-40);
        }
    }
}

// ---- wide spike-layer GEMM: block 128x64, 4 waves 2x2, wave 64x32 (Mf=2) ----
template<int KP>
__global__ __launch_bounds__(256)
void gemm32w(const signed char* __restrict__ Asp,
             const signed char* __restrict__ Wp, size_t planeW,
             double* __restrict__ curout)
{
    __shared__ __align__(16) signed char Wld[5 * 64 * 80];   // 25.6 KB
    __shared__ __align__(16) signed char Ald[128 * 80];      // 10.2 KB
    constexpr int NIT = KP / 64;

    const int tid = threadIdx.x;
    const int l   = tid & 63;
    const int w   = tid >> 6;           // 0..3
    const int wm  = (w & 1) * 64;       // 0/64
    const int wn  = (w >> 1) * 32;      // 0/32
    const int r32 = l & 31;
    const int h   = l >> 5;

    const int bm = blockIdx.y * 128;
    const int bn = blockIdx.x * 64;

    const int srA = tid >> 1;           // 0..127
    const int scA = (tid & 1) * 32;
    const int srW = tid >> 2;           // 0..63
    const int scW = (tid & 3) * 16;

    const signed char* ag = Asp + (size_t)(bm + srA) * KP + scA;
    const signed char* wg = Wp  + (size_t)(bn + srW) * KP + scW;

    int4v Ar0 = *(const int4v*)(ag);
    int4v Ar1 = *(const int4v*)(ag + 16);
    int4v Wr[5];
#pragma unroll
    for (int p = 0; p < 5; ++p) Wr[p] = *(const int4v*)(wg + p * planeW);

    int16v acc[2][5];
#pragma unroll
    for (int mi = 0; mi < 2; ++mi)
#pragma unroll
        for (int s = 0; s < 5; ++s)
#pragma unroll
            for (int r = 0; r < 16; ++r) acc[mi][s][r] = 0;

    for (int it = 0; it < NIT; ++it) {
        __syncthreads();
#pragma unroll
        for (int p = 0; p < 5; ++p)
            *(int4v*)&Wld[(p * 64 + srW) * 80 + scW] = Wr[p];
        *(int4v*)&Ald[srA * 80 + scA]      = Ar0;
        *(int4v*)&Ald[srA * 80 + scA + 16] = Ar1;
        __syncthreads();

        if (it + 1 < NIT) {
            int kb = (it + 1) * 64;
            Ar0 = *(const int4v*)(ag + kb);
            Ar1 = *(const int4v*)(ag + kb + 16);
#pragma unroll
            for (int p = 0; p < 5; ++p)
                Wr[p] = *(const int4v*)(wg + kb + p * planeW);
        }

#pragma unroll
        for (int k2 = 0; k2 < 2; ++k2) {
            const int off = k2 * 32 + 16 * h;
            int4v bq[5];
#pragma unroll
            for (int q = 0; q < 5; ++q)
                bq[q] = *(const int4v*)&Wld[(q * 64 + wn + r32) * 80 + off];
#pragma unroll
            for (int mi = 0; mi < 2; ++mi) {
                int4v a0 = *(const int4v*)&Ald[(wm + mi * 32 + r32) * 80 + off];
#pragma unroll
                for (int q = 0; q < 5; ++q)
                    acc[mi][q] = __builtin_amdgcn_mfma_i32_32x32x32_i8(
                        a0, bq[q], acc[mi][q], 0, 0, 0);
            }
        }
    }

    const int col = bn + wn + r32;
#pragma unroll
    for (int mi = 0; mi < 2; ++mi)
#pragma unroll
        for (int reg = 0; reg < 16; ++reg) {
            int row = bm + wm + mi * 32 + (reg & 3) + 8 * (reg >> 2) + 4 * h;
            double v = (double)acc[mi][4][reg];
            v = v * 256.0 + (double)acc[mi][3][reg];
            v = v * 256.0 + (double)acc[mi][2][reg];
            v = v * 256.0 + (double)acc[mi][1][reg];
            v = v * 256.0 + (double)acc[mi][0][reg];
            curout[(size_t)row * 1024 + col] = v * 0x1p-40;
        }
}

// ---- leaky-IF over ALL 50 t, 2 adjacent cols per thread, state in regs ----
__global__ __launch_bounds__(256)
void if_update(const double* __restrict__ cur, const float* __restrict__ bias,
               float* __restrict__ spk, float* __restrict__ mem,
               signed char* __restrict__ spk_i8)
{
    int idx = blockIdx.x * blockDim.x + threadIdx.x;     // 512*500
    if (idx >= 512 * 500) return;
    int row = idx / 500, col = (idx - row * 500) * 2;
    double mp0 = 0.0, mp1 = 0.0;
    double bs0 = (double)bias[col], bs1 = (double)bias[col + 1];
    for (int t = 0; t < 50; ++t) {
        double2 c = *(const double2*)&cur[((size_t)t * 512 + row) * 1024 + col];
        double rst0 = (mp0 > 1.0) ? 1.0 : 0.0;
        double rst1 = (mp1 > 1.0) ? 1.0 : 0.0;
        double mn0 = 0.9 * mp0 + (c.x + bs0) - rst0;
        double mn1 = 0.9 * mp1 + (c.y + bs1) - rst1;
        int s0 = (mn0 > 1.0) ? 1 : 0;
        int s1 = (mn1 > 1.0) ? 1 : 0;
        size_t o = ((size_t)t * 512 + row) * 1000 + col;
        *(float2*)&spk[o] = make_float2((float)s0, (float)s1);
        *(float2*)&mem[o] = make_float2((float)mn0, (float)mn1);
        *(short*)&spk_i8[((size_t)t * 512 + row) * 1024 + col] =
            (short)(s0 | (s1 << 8));
        mp0 = mn0; mp1 = mn1;
    }
}

// ---- layer-3 IF chain: 5120 neurons, all 50 t in registers ----
__global__ __launch_bounds__(256)
void if3_kernel(const double* __restrict__ cur3, const float* __restrict__ bias,
                float* __restrict__ spk3, float* __restrict__ mem3)
{
    int idx = blockIdx.x * blockDim.x + threadIdx.x;
    if (idx >= 5120) return;
    int brow = idx / 10, col = idx - brow * 10;
    double bs = (double)bias[col];
    double mp = 0.0;
    for (int t = 0; t < 50; ++t) {
        double c   = cur3[((size_t)t * 512 + brow) * 16 + col] + bs;
        double rst = (mp > 1.0) ? 1.0 : 0.0;
        double mn  = 0.9 * mp + c - rst;
        size_t o   = (size_t)t * 5120 + (size_t)brow * 10 + col;
        spk3[o] = (mn > 1.0) ? 1.0f : 0.0f;
        mem3[o] = (float)mn;
        mp = mn;
    }
}

extern "C" void kernel_launch(void* const* d_in, const int* in_sizes, int n_in,
                              void* d_out, int out_size, void* d_ws, size_t ws_size,
                              hipStream_t stream)
{
    const float* x  = (const float*)d_in[0];
    const float* W0 = (const float*)d_in[1];
    const float* b0 = (const float*)d_in[2];
    const float* W1 = (const float*)d_in[3];
    const float* b1 = (const float*)d_in[4];
    const float* W2 = (const float*)d_in[5];
    const float* b2 = (const float*)d_in[6];
    const float* W3 = (const float*)d_in[7];
    const float* b3 = (const float*)d_in[8];
    float* out = (float*)d_out;

    const int T = 50;
    const size_t LNH = (size_t)512 * 1000;
    const size_t LNO = (size_t)512 * 10;

    float* spk0 = out;
    float* spk1 = spk0 + (size_t)T * LNH;
    float* spk2 = spk1 + (size_t)T * LNH;
    float* spk3 = spk2 + (size_t)T * LNH;
    float* mem0 = spk3 + (size_t)T * LNO;
    float* mem1 = mem0 + (size_t)T * LNH;
    float* mem2 = mem1 + (size_t)T * LNH;
    float* mem3 = mem2 + (size_t)T * LNH;

    // ---- workspace layout (fp64 first, then i8); total ~410 MB ----
    double* cur = (double*)d_ws;                          // 25600*1024*8 = 210 MB
    signed char* W0d = (signed char*)(cur + (size_t)MT * 1024);   // 5*1024*832
    signed char* W1d = W0d + (size_t)5 * 1024 * 832;      // 5*1024*1024
    signed char* W2d = W1d + (size_t)5 * 1024 * 1024;
    signed char* W3d = W2d + (size_t)5 * 1024 * 1024;     // 5*64*1024
    signed char* xsb = W3d + (size_t)5 * 64 * 1024;       // 5*25600*832 = 106.5 MB
    signed char* sp0 = xsb + (size_t)5 * MT * 832;        // 25600*1024 = 26.2 MB
    signed char* sp1 = sp0 + (size_t)MT * 1024;
    signed char* sp2 = sp1 + (size_t)MT * 1024;

    // zero spike buffers once (K-tail cols 1000..1023 must stay 0)
    hipMemsetAsync(sp0, 0, (size_t)3 * MT * 1024, stream);

    // W digit splits
    wsplit_i8<<<(1024 * 832  + 255) / 256, 256, 0, stream>>>(W0, W0d, 1000, 1024, 784,  832);
    wsplit_i8<<<(1024 * 1024 + 255) / 256, 256, 0, stream>>>(W1, W1d, 1000, 1024, 1000, 1024);
    wsplit_i8<<<(1024 * 1024 + 255) / 256, 256, 0, stream>>>(W2, W2d, 1000, 1024, 1000, 1024);
    wsplit_i8<<<(64 * 1024   + 255) / 256, 256, 0, stream>>>(W3, W3d, 10,   64,   1000, 1024);

    // x digitize, all 50 t
    xsplit_all<<<(MT * 832 + 255) / 256, 256, 0, stream>>>(x, xsb);

    const size_t plA0 = (size_t)MT * 832;
    const size_t plW0 = (size_t)1024 * 832;
    const size_t plWH = (size_t)1024 * 1024;
    const size_t plW3 = (size_t)64 * 1024;

    dim3 blk(256);
    dim3 g0(16, MT / 64);     // L0: 64x64 tiles  -> 6400 blocks
    dim3 gW(16, MT / 128);    // L1/L2: 128x64    -> 3200 blocks
    dim3 g3(1, MT / 64);      // L3: 64x64, N=16  -> 400 blocks

    // L0
    gemm32<5, 832, 1024><<<g0, blk, 0, stream>>>(xsb, plA0, W0d, plW0, cur);
    if_update<<<1000, 256, 0, stream>>>(cur, b0, spk0, mem0, sp0);
    // L1
    gemm32w<1024><<<gW, blk, 0, stream>>>(sp0, W1d, plWH, cur);
    if_update<<<1000, 256, 0, stream>>>(cur, b1, spk1, mem1, sp1);
    // L2
    gemm32w<1024><<<gW, blk, 0, stream>>>(sp1, W2d, plWH, cur);
    if_update<<<1000, 256, 0, stream>>>(cur, b2, spk2, mem2, sp2);
    // L3
    gemm32<1, 1024, 16><<<g3, blk, 0, stream>>>(sp2, 0, W3d, plW3, cur);
    if3_kernel<<<20, 256, 0, stream>>>(cur, b3, spk3, mem3);
}